// Round 3
// baseline (199.676 us; speedup 1.0000x reference)
//
#include <hip/hip_runtime.h>

namespace {
constexpr int IW = 512;
constexpr int IH = 512;
constexpr int ID = 64;
constexpr int PS = IH * IW;                      // plane stride (floats)
constexpr float W_Z  = 0.5f;                     // CONTIZ^2
constexpr float W_XY = 2.0f;
constexpr float W_XZ = 1.41421356237309515f;     // 2*CONTIZ = sqrt(2)

constexpr int TPB    = 256;
constexpr int NSEG   = 4;                        // z segments
constexpr int DSEG   = ID / NSEG;                // 16 d-steps per segment
constexpr int BLOCKS = 2 * NSEG * IH * 64 / TPB; // 1024 (4 rows/block)
}

__device__ __forceinline__ void ld8(const float* p, float v[8]) {
    float4 r0 = *(const float4*)p;
    float4 r1 = *(const float4*)(p + 4);
    v[0] = r0.x; v[1] = r0.y; v[2] = r0.z; v[3] = r0.w;
    v[4] = r1.x; v[5] = r1.y; v[6] = r1.z; v[7] = r1.w;
}

// 4 waves/block, one row per wave; 128 VGPR cap -> 4 waves/SIMD.
__global__ __launch_bounds__(TPB, 4) void HessianReg_kernel(const float* __restrict__ img,
                                                            float* __restrict__ out) {
    // 8 bands = (n,seg) x 512 rows. XCD k owns band k entirely:
    // z-window working set ~3-4 MB fits one XCD's 4 MiB L2.
    const int lblk = (blockIdx.x & 7) * (BLOCKS / 8) + (blockIdx.x >> 3);
    const int tid  = threadIdx.x;
    const int lane = tid & 63;
    const int r    = lblk * (TPB / 64) + (tid >> 6);   // row task [0,4096)
    const int h    = r & (IH - 1);
    const int q    = r >> 9;                           // band id [0,8) == XCD
    const int n    = q & 1;
    const int seg  = q >> 1;
    const int d0   = __builtin_amdgcn_readfirstlane(seg * DSEG);
    const int w0   = lane << 3;                        // 8 floats per lane

    // lane 63 owns the row end: its tail (w0+8..) does not exist -> masked.
    const float mh = (lane < 63) ? 1.f : 0.f;
    const bool hy2 = (h < IH - 1);   // wave-uniform
    const bool hy3 = (h < IH - 2);   // wave-uniform

    const float* p = img + (size_t)((n * ID + d0) * IH + h) * IW + w0;

    // ---- prologue: rows A=(d0,h), B=(d0,h+1), E=(d0+1,h) ----
    float Av[8], Bv[8], Ev[8];
    ld8(p, Av);
    float a8 = __shfl_down(Av[0], 1, 64);   // lane+1's leading elems = our tail
    float a9 = __shfl_down(Av[1], 1, 64);
    #pragma unroll
    for (int i = 0; i < 8; ++i) Bv[i] = 0.f;
    float b8 = 0.f;
    if (hy2) { ld8(p + IW, Bv); b8 = __shfl_down(Bv[0], 1, 64); }
    ld8(p + PS, Ev);                         // d0+1 <= 49: always valid
    float e8 = __shfl_down(Ev[0], 1, 64);
    float e9 = __shfl_down(Ev[1], 1, 64);

    // x first-differences (9 per row for the gxx chain; 8 for B)
    float dxA[9], dxE[9], dxB[8];
    #pragma unroll
    for (int i = 0; i < 7; ++i) dxA[i] = Av[i + 1] - Av[i];
    dxA[7] = a8 - Av[7]; dxA[8] = a9 - a8;
    #pragma unroll
    for (int i = 0; i < 7; ++i) dxE[i] = Ev[i + 1] - Ev[i];
    dxE[7] = e8 - Ev[7]; dxE[8] = e9 - e8;
    #pragma unroll
    for (int i = 0; i < 7; ++i) dxB[i] = Bv[i + 1] - Bv[i];
    dxB[7] = b8 - Bv[7];

    float dy1[8], dz1[8];
    #pragma unroll
    for (int i = 0; i < 8; ++i) { dy1[i] = Bv[i] - Av[i]; dz1[i] = Ev[i] - Av[i]; }

    float sxx = 0.f, syy = 0.f, szz = 0.f, sxy = 0.f, sxz = 0.f, syz = 0.f;

    #pragma unroll 2
    for (int dl = 0; dl < DSEG; ++dl) {
        const int d = d0 + dl;
        const bool gz2 = (d < ID - 1);   // wave-uniform z guards
        const bool gz3 = (d < ID - 2);

        // ---- fresh rows: C=(d,h+2) G=(d+1,h+1) F=(d+2,h) — contiguous b128 only
        float Cv[8], Gv[8], Fv[8];
        #pragma unroll
        for (int i = 0; i < 8; ++i) { Cv[i] = 0.f; Gv[i] = 0.f; Fv[i] = 0.f; }
        if (hy3)        ld8(p + 2 * IW,     Cv);
        if (gz2 && hy2) ld8(p + PS + IW,    Gv);
        if (gz3)        ld8(p + 2 * PS,     Fv);

        // ---- stencils on rolled state (covers load latency) ----
        // g_xx: |dx[i+1]-dx[i]|; last two terms boundary-masked (lane 63)
        #pragma unroll
        for (int i = 0; i < 6; ++i) sxx += fabsf(dxA[i + 1] - dxA[i]);
        sxx = fmaf(mh, fabsf(dxA[7] - dxA[6]), sxx);
        sxx = fmaf(mh, fabsf(dxA[8] - dxA[7]), sxx);
        if (hy2) {                        // g_xy = |dxB - dxA|
            #pragma unroll
            for (int i = 0; i < 7; ++i) sxy += fabsf(dxB[i] - dxA[i]);
            sxy = fmaf(mh, fabsf(dxB[7] - dxA[7]), sxy);
        }
        if (gz2) {                        // g_xz = |dxE - dxA|
            #pragma unroll
            for (int i = 0; i < 7; ++i) sxz += fabsf(dxE[i] - dxA[i]);
            sxz = fmaf(mh, fabsf(dxE[7] - dxA[7]), sxz);
        }

        // tails of fresh rows: in-wave shuffles replace strided VMEM loads
        float g8 = __shfl_down(Gv[0], 1, 64);
        float f8 = __shfl_down(Fv[0], 1, 64);
        float f9 = __shfl_down(Fv[1], 1, 64);

        // ---- fresh diffs + y/z stencils ----
        if (hy3) {                        // g_yy = |(C-B) - dy1|
            #pragma unroll
            for (int i = 0; i < 8; ++i) syy += fabsf((Cv[i] - Bv[i]) - dy1[i]);
        }
        float dyEG[8], dz2[8];
        #pragma unroll
        for (int i = 0; i < 8; ++i) dyEG[i] = Gv[i] - Ev[i];
        if (gz2 && hy2) {                 // g_yz = |dyEG - dy1|
            #pragma unroll
            for (int i = 0; i < 8; ++i) syz += fabsf(dyEG[i] - dy1[i]);
        }
        #pragma unroll
        for (int i = 0; i < 8; ++i) dz2[i] = Fv[i] - Ev[i];
        if (gz3) {                        // g_zz = |dz2 - dz1|
            #pragma unroll
            for (int i = 0; i < 8; ++i) szz += fabsf(dz2[i] - dz1[i]);
        }

        // ---- roll z (unroll 2 renames the period-2 dxA<-dxE chain away) ----
        #pragma unroll
        for (int i = 0; i < 9; ++i) dxA[i] = dxE[i];
        #pragma unroll
        for (int i = 0; i < 7; ++i) dxE[i] = Fv[i + 1] - Fv[i];
        dxE[7] = f8 - Fv[7]; dxE[8] = f9 - f8;
        #pragma unroll
        for (int i = 0; i < 7; ++i) dxB[i] = Gv[i + 1] - Gv[i];
        dxB[7] = g8 - Gv[7];
        #pragma unroll
        for (int i = 0; i < 8; ++i) {
            Bv[i] = Gv[i]; Ev[i] = Fv[i];
            dy1[i] = dyEG[i]; dz1[i] = dz2[i];
        }
        p += PS;
    }

    float acc = sxx + syy + W_Z * szz + W_XY * sxy + W_XZ * (sxz + syz);

    // wave (64-lane) shuffle reduce
    for (int off = 32; off > 0; off >>= 1)
        acc += __shfl_down(acc, off, 64);

    __shared__ float ws[TPB / 64];
    const int wv = tid >> 6;
    if (lane == 0) ws[wv] = acc;
    __syncthreads();
    if (tid == 0) {
        float bsum = 0.f;
        #pragma unroll
        for (int i = 0; i < TPB / 64; ++i) bsum += ws[i];
        atomicAdd(out, bsum * (1.0f / (IH * IW)));
    }
}

extern "C" void kernel_launch(void* const* d_in, const int* in_sizes, int n_in,
                              void* d_out, int out_size, void* d_ws, size_t ws_size,
                              hipStream_t stream) {
    const float* img = (const float*)d_in[0];
    float* out = (float*)d_out;
    // d_out is re-poisoned to 0xAA before every timed launch -> zero it on-stream.
    hipMemsetAsync(out, 0, sizeof(float), stream);
    hipLaunchKernelGGL(HessianReg_kernel, dim3(BLOCKS), dim3(TPB), 0, stream, img, out);
}

// Round 4
// 191.585 us; speedup vs baseline: 1.0422x; 1.0422x over previous
//
#include <hip/hip_runtime.h>

namespace {
constexpr int IW = 512;
constexpr int IH = 512;
constexpr int ID = 64;
constexpr int PS = IH * IW;                      // plane stride (floats)
constexpr float W_Z  = 0.5f;                     // CONTIZ^2
constexpr float W_XY = 2.0f;
constexpr float W_XZ = 1.41421356237309515f;     // 2*CONTIZ = sqrt(2)

constexpr int TPB    = 256;
constexpr int NSEG   = 4;                        // z segments
constexpr int DSEG   = ID / NSEG;                // 16 d-steps per segment
// one wave = one anchor-row PAIR: 2(n) x 4(seg) x 256(pairs) = 2048 waves
constexpr int BLOCKS = 2 * NSEG * (IH / 2) / (TPB / 64);   // 512
}

__device__ __forceinline__ void ld8(const float* p, float v[8]) {
    float4 r0 = *(const float4*)p;
    float4 r1 = *(const float4*)(p + 4);
    v[0] = r0.x; v[1] = r0.y; v[2] = r0.z; v[3] = r0.w;
    v[4] = r1.x; v[5] = r1.y; v[6] = r1.z; v[7] = r1.w;
}
__device__ __forceinline__ void zero8(float v[8]) {
    #pragma unroll
    for (int i = 0; i < 8; ++i) v[i] = 0.f;
}
// x first-differences of an 8-float lane chunk (+2 tail elems via shuffle)
__device__ __forceinline__ void dx9(const float v[8], float t8, float t9, float o[9]) {
    #pragma unroll
    for (int i = 0; i < 7; ++i) o[i] = v[i + 1] - v[i];
    o[7] = t8 - v[7];
    o[8] = t9 - t8;
}

// 4 waves/block; 2 blocks/CU (grid-limited) -> VGPR budget 256
__global__ __launch_bounds__(TPB, 2) void HessianReg_kernel(const float* __restrict__ img,
                                                            float* __restrict__ out) {
    // XCD k owns band k = (n,seg) entirely: 64 consecutive logical blocks.
    const int lblk = (blockIdx.x & 7) * (BLOCKS / 8) + (blockIdx.x >> 3);
    const int tid  = threadIdx.x;
    const int lane = tid & 63;
    const int P    = lblk * (TPB / 64) + (tid >> 6);   // pair task [0,2048)
    const int h2   = P & 255;
    const int q    = P >> 8;                           // band id [0,8) == XCD
    const int n    = q & 1;
    const int seg  = q >> 1;
    const int h    = h2 << 1;                          // even anchor row
    const int d0   = __builtin_amdgcn_readfirstlane(seg * DSEG);
    const int w0   = lane << 3;

    const float mh = (lane < 63) ? 1.f : 0.f;  // x-tail mask (row end)
    const bool ry2 = (h < IH - 2);             // row h+2 exists (false only h=510)
    const bool ry3 = (h < IH - 3);             // row h+3 exists

    const float* p = img + ((size_t)(n * ID + d0) * IH + h) * IW + w0;

    // ---- prologue: slabs of planes d0 and d0+1 (rows h..h+3) ----
    float Vc[4][8], Vp[4][8];
    ld8(p, Vc[0]); ld8(p + IW, Vc[1]);
    if (ry2) ld8(p + 2 * IW, Vc[2]); else zero8(Vc[2]);
    if (ry3) ld8(p + 3 * IW, Vc[3]); else zero8(Vc[3]);
    ld8(p + PS, Vp[0]); ld8(p + PS + IW, Vp[1]);       // d0+1 <= 49: valid
    if (ry2) ld8(p + PS + 2 * IW, Vp[2]); else zero8(Vp[2]);
    if (ry3) ld8(p + PS + 3 * IW, Vp[3]); else zero8(Vp[3]);

    // rolled state (all first-difference form):
    // DXc/DXn: x-diffs rows 0..2 at planes d, d+1
    // DYc/DYn: y-diffs (row j+1 - row j), j=0..2, at planes d, d+1
    // DZc    : z-diff  (plane d+1 - plane d), rows 0..1
    // Vn0/Vn1: plane d+1 values rows 0..1 (for next DZ)
    float DXc[3][9], DXn[3][9], DYc[3][8], DYn[3][8], DZc[2][8];
    float Vn0[8], Vn1[8];
    #pragma unroll
    for (int j = 0; j < 3; ++j) {
        float c8 = __shfl_down(Vc[j][0], 1, 64);
        float c9 = __shfl_down(Vc[j][1], 1, 64);
        dx9(Vc[j], c8, c9, DXc[j]);
        float p8 = __shfl_down(Vp[j][0], 1, 64);
        float p9 = __shfl_down(Vp[j][1], 1, 64);
        dx9(Vp[j], p8, p9, DXn[j]);
        #pragma unroll
        for (int i = 0; i < 8; ++i) {
            DYc[j][i] = Vc[j + 1][i] - Vc[j][i];
            DYn[j][i] = Vp[j + 1][i] - Vp[j][i];
        }
    }
    #pragma unroll
    for (int i = 0; i < 8; ++i) {
        DZc[0][i] = Vp[0][i] - Vc[0][i];
        DZc[1][i] = Vp[1][i] - Vc[1][i];
        Vn0[i] = Vp[0][i]; Vn1[i] = Vp[1][i];
    }

    float sxx = 0.f, syy = 0.f, szz = 0.f, sxy = 0.f, sxz = 0.f, syz = 0.f;

    #pragma unroll 2
    for (int dl = 0; dl < DSEG; ++dl) {
        const int d = d0 + dl;
        const bool gz1 = (d < ID - 1);   // g_xz/g_yz valid (needs plane d+1)
        const bool gz2 = (d < ID - 2);   // g_zz valid == plane d+2 exists

        // ---- load slab of plane d+2: each row exactly once per wave ----
        float Vf[4][8];
        if (gz2) {
            ld8(p + 2 * PS, Vf[0]); ld8(p + 2 * PS + IW, Vf[1]);
            if (ry2) ld8(p + 2 * PS + 2 * IW, Vf[2]); else zero8(Vf[2]);
            if (ry3) ld8(p + 2 * PS + 3 * IW, Vf[3]); else zero8(Vf[3]);
        } else {
            zero8(Vf[0]); zero8(Vf[1]); zero8(Vf[2]); zero8(Vf[3]);
        }
        float f8[3], f9[3];
        #pragma unroll
        for (int j = 0; j < 3; ++j) {
            f8[j] = __shfl_down(Vf[j][0], 1, 64);
            f9[j] = __shfl_down(Vf[j][1], 1, 64);
        }

        // ---- accumulate anchors (d, h) and (d, h+1) from rolled state ----
        // g_xx: second x-diffs, rows j=0,1 (last two terms lane63-masked)
        #pragma unroll
        for (int j = 0; j < 2; ++j) {
            #pragma unroll
            for (int i = 0; i < 6; ++i) sxx += fabsf(DXc[j][i + 1] - DXc[j][i]);
            sxx = fmaf(mh, fabsf(DXc[j][7] - DXc[j][6]), sxx);
            sxx = fmaf(mh, fabsf(DXc[j][8] - DXc[j][7]), sxx);
        }
        // g_xy = |dx(row j+1) - dx(row j)|, anchors j=0 (always), j=1 (ry2)
        {
            #pragma unroll
            for (int i = 0; i < 7; ++i) sxy += fabsf(DXc[1][i] - DXc[0][i]);
            sxy = fmaf(mh, fabsf(DXc[1][7] - DXc[0][7]), sxy);
            if (ry2) {
                #pragma unroll
                for (int i = 0; i < 7; ++i) sxy += fabsf(DXc[2][i] - DXc[1][i]);
                sxy = fmaf(mh, fabsf(DXc[2][7] - DXc[1][7]), sxy);
            }
        }
        // g_xz = |dx(plane d+1) - dx(plane d)|, rows j=0,1
        if (gz1) {
            #pragma unroll
            for (int j = 0; j < 2; ++j) {
                #pragma unroll
                for (int i = 0; i < 7; ++i) sxz += fabsf(DXn[j][i] - DXc[j][i]);
                sxz = fmaf(mh, fabsf(DXn[j][7] - DXc[j][7]), sxz);
            }
        }
        // g_yy = |dy(j+1) - dy(j)|, anchors j=0 (ry2), j=1 (ry3)
        if (ry2) {
            #pragma unroll
            for (int i = 0; i < 8; ++i) syy += fabsf(DYc[1][i] - DYc[0][i]);
        }
        if (ry3) {
            #pragma unroll
            for (int i = 0; i < 8; ++i) syy += fabsf(DYc[2][i] - DYc[1][i]);
        }
        // g_yz = |dy(plane d+1) - dy(plane d)|, anchors j=0 (always), j=1 (ry2)
        if (gz1) {
            #pragma unroll
            for (int i = 0; i < 8; ++i) syz += fabsf(DYn[0][i] - DYc[0][i]);
            if (ry2) {
                #pragma unroll
                for (int i = 0; i < 8; ++i) syz += fabsf(DYn[1][i] - DYc[1][i]);
            }
        }
        // g_zz = |dz(d+1->d+2) - dz(d->d+1)|, rows j=0,1; then roll DZ
        {
            float dzf0[8], dzf1[8];
            #pragma unroll
            for (int i = 0; i < 8; ++i) { dzf0[i] = Vf[0][i] - Vn0[i]; dzf1[i] = Vf[1][i] - Vn1[i]; }
            if (gz2) {
                #pragma unroll
                for (int i = 0; i < 8; ++i) szz += fabsf(dzf0[i] - DZc[0][i]);
                #pragma unroll
                for (int i = 0; i < 8; ++i) szz += fabsf(dzf1[i] - DZc[1][i]);
            }
            #pragma unroll
            for (int i = 0; i < 8; ++i) { DZc[0][i] = dzf0[i]; DZc[1][i] = dzf1[i]; }
        }

        // ---- roll planes (copies renamed away by unroll 2) ----
        #pragma unroll
        for (int j = 0; j < 3; ++j) {
            #pragma unroll
            for (int i = 0; i < 9; ++i) DXc[j][i] = DXn[j][i];
            #pragma unroll
            for (int i = 0; i < 8; ++i) DYc[j][i] = DYn[j][i];
        }
        #pragma unroll
        for (int j = 0; j < 3; ++j) {
            dx9(Vf[j], f8[j], f9[j], DXn[j]);
            #pragma unroll
            for (int i = 0; i < 8; ++i) DYn[j][i] = Vf[j + 1][i] - Vf[j][i];
        }
        #pragma unroll
        for (int i = 0; i < 8; ++i) { Vn0[i] = Vf[0][i]; Vn1[i] = Vf[1][i]; }
        p += PS;
    }

    float acc = sxx + syy + W_Z * szz + W_XY * sxy + W_XZ * (sxz + syz);

    // wave (64-lane) shuffle reduce
    for (int off = 32; off > 0; off >>= 1)
        acc += __shfl_down(acc, off, 64);

    __shared__ float ws[TPB / 64];
    const int wv = tid >> 6;
    if (lane == 0) ws[wv] = acc;
    __syncthreads();
    if (tid == 0) {
        float bsum = 0.f;
        #pragma unroll
        for (int i = 0; i < TPB / 64; ++i) bsum += ws[i];
        atomicAdd(out, bsum * (1.0f / (IH * IW)));
    }
}

extern "C" void kernel_launch(void* const* d_in, const int* in_sizes, int n_in,
                              void* d_out, int out_size, void* d_ws, size_t ws_size,
                              hipStream_t stream) {
    const float* img = (const float*)d_in[0];
    float* out = (float*)d_out;
    // d_out is re-poisoned to 0xAA before every timed launch -> zero it on-stream.
    hipMemsetAsync(out, 0, sizeof(float), stream);
    hipLaunchKernelGGL(HessianReg_kernel, dim3(BLOCKS), dim3(TPB), 0, stream, img, out);
}